// Round 1
// baseline (154.253 us; speedup 1.0000x reference)
//
#include <hip/hip_runtime.h>
#include <hip/hip_bf16.h>
#include <math.h>

// Problem: Hausdorff distance loss.
// pred  [16, 2, 256, 256] f32 logits; target [16, 256, 256] i32 {0,1}.
// pred_lbl = (pred[:,1] > pred[:,0])           (argmax over C=2, ties -> 0)
// dt(mask) = exact EDT: row cummax pass (1D exact) then column min-plus.
// out = 0.5 * ( mean(pred_lbl * dt(target)) + mean(target * dt(pred_lbl)) )

#define B 16
#define H 256
#define W 256
#define IMG (H * W)            // 65536
#define NPIX (B * IMG)         // 1048576
#define NEGF (-1.0e6f)

// ---------------------------------------------------------------------------
// Kernel 1: row pass. One block (256 thr) per (mask, b, y) row.
// Computes g2[m][b][y][x] = min(dl, dr)^2  exactly like the reference:
//   dl = x - cummax(fg ? x : NEG)
//   dr = -cummax_rev(fg ? -x : NEG) - x
__global__ __launch_bounds__(256) void rowpass_kernel(
    const float* __restrict__ pred, const int* __restrict__ target,
    float* __restrict__ g2) {
  __shared__ float s[256];
  const int t = threadIdx.x;
  const int bi = blockIdx.x;           // [0, 2*B*H)
  const int m = bi >> 12;              // 0: pred mask, 1: target mask
  const int bh = bi & 4095;
  const int b = bh >> 8;
  const int y = bh & 255;

  bool fg;
  if (m == 0) {
    const float* base = pred + (size_t)b * (2 * IMG) + y * W + t;
    fg = base[IMG] > base[0];          // pred[b,1,y,t] > pred[b,0,y,t]
  } else {
    fg = target[(size_t)b * IMG + y * W + t] == 1;
  }
  const float xi = (float)t;

  // inclusive cummax left->right of pos_l
  float v = fg ? xi : NEGF;
  s[t] = v;
  __syncthreads();
  for (int off = 1; off < 256; off <<= 1) {
    float o = (t >= off) ? s[t - off] : -3.0e38f;
    __syncthreads();
    v = fmaxf(v, o);
    s[t] = v;
    __syncthreads();
  }
  const float dl = xi - v;

  // inclusive cummax over reversed order of pos_r = fg ? -x : NEG
  float w = fg ? -xi : NEGF;
  const int r = 255 - t;               // scan position
  s[r] = w;
  __syncthreads();
  for (int off = 1; off < 256; off <<= 1) {
    float o = (r >= off) ? s[r - off] : -3.0e38f;
    __syncthreads();
    w = fmaxf(w, o);
    s[r] = w;
    __syncthreads();
  }
  const float dr = -w - xi;

  const float dmin = fminf(dl, dr);
  g2[(size_t)m * NPIX + (size_t)b * IMG + y * W + t] = dmin * dmin;
}

// ---------------------------------------------------------------------------
// Kernel 2: column min-plus + fused weighted-sum reduction.
// Block = 256 thr handles (b, m, xt, yg): columns [xt*64, xt*64+64),
// output rows [yg*64, yg*64+64). Thread = (xin = tid&63, ysub = tid>>6),
// owns 16 accumulators (y = yg*64 + ysub*16 + k).
__global__ __launch_bounds__(256) void colpass_kernel(
    const float* __restrict__ g2, const float* __restrict__ pred,
    const int* __restrict__ target, float* __restrict__ sums) {
  __shared__ float lds[256][64];       // 64 KB: g2 column slab [y'][xin]
  const int tid = threadIdx.x;
  const int bi = blockIdx.x;           // [0, 512)
  const int xt = bi & 3;
  const int yg = (bi >> 2) & 3;
  const int m = (bi >> 4) & 1;
  const int b = bi >> 5;

  const float* gimg = g2 + (size_t)m * NPIX + (size_t)b * IMG;
  const int x0 = xt * 64;

  // stage 64 columns x 256 rows into LDS (coalesced, 64 loads/thread)
  for (int i = 0; i < 64; ++i) {
    int flat = i * 256 + tid;          // 0..16383
    int yp = flat >> 6;
    int xin = flat & 63;
    lds[yp][xin] = gimg[yp * W + x0 + xin];
  }
  __syncthreads();

  const int xin = tid & 63;
  const int ysub = tid >> 6;
  const int ybase = yg * 64 + ysub * 16;

  float acc[16];
#pragma unroll
  for (int k = 0; k < 16; ++k) acc[k] = 3.4e38f;

  for (int yp = 0; yp < 256; ++yp) {
    const float v = lds[yp][xin];
    const float dbase = (float)(ybase - yp);
#pragma unroll
    for (int k = 0; k < 16; ++k) {
      const float d = dbase + (float)k;
      acc[k] = fminf(acc[k], fmaf(d, d, v));
    }
  }

  // epilogue: dt = sqrt(dt2); weight by the OTHER mask; local sum
  const int x = x0 + xin;
  float local = 0.f;
#pragma unroll
  for (int k = 0; k < 16; ++k) {
    const int y = ybase + k;
    float wgt;
    if (m == 0) {
      // dt of pred_lbl, weighted by target
      wgt = (float)target[(size_t)b * IMG + y * W + x];
    } else {
      // dt of target, weighted by pred_lbl
      const float* p = pred + (size_t)b * (2 * IMG) + y * W + x;
      wgt = (p[IMG] > p[0]) ? 1.f : 0.f;
    }
    local += wgt * sqrtf(acc[k]);
  }

  // block tree-reduce (reuse LDS) + one atomic per block
  __syncthreads();
  float* red = &lds[0][0];
  red[tid] = local;
  __syncthreads();
  for (int s = 128; s > 0; s >>= 1) {
    if (tid < s) red[tid] += red[tid + s];
    __syncthreads();
  }
  if (tid == 0) atomicAdd(&sums[m], red[0]);
}

// ---------------------------------------------------------------------------
__global__ void init_kernel(float* __restrict__ sums) {
  if (threadIdx.x < 2) sums[threadIdx.x] = 0.f;
}

__global__ void finalize_kernel(const float* __restrict__ sums,
                                float* __restrict__ out) {
  // (mean_t2p + mean_p2t) / 2 ; ALPHA = 1
  out[0] = (sums[0] + sums[1]) * (0.5f / (float)NPIX);
}

// ---------------------------------------------------------------------------
extern "C" void kernel_launch(void* const* d_in, const int* in_sizes, int n_in,
                              void* d_out, int out_size, void* d_ws, size_t ws_size,
                              hipStream_t stream) {
  const float* pred = (const float*)d_in[0];     // [16,2,256,256] f32
  const int* target = (const int*)d_in[1];       // [16,256,256] i32
  float* out = (float*)d_out;                    // scalar f32

  float* g2 = (float*)d_ws;                      // 2 * NPIX floats (8 MB)
  float* sums = g2 + 2 * (size_t)NPIX;           // 2 floats

  init_kernel<<<1, 64, 0, stream>>>(sums);
  rowpass_kernel<<<2 * B * H, 256, 0, stream>>>(pred, target, g2);
  colpass_kernel<<<512, 256, 0, stream>>>(g2, pred, target, sums);
  finalize_kernel<<<1, 1, 0, stream>>>(sums, out);
}

// Round 2
// 101.624 us; speedup vs baseline: 1.5179x; 1.5179x over previous
//
#include <hip/hip_runtime.h>
#include <hip/hip_bf16.h>
#include <math.h>

// Hausdorff distance loss, exact EDT.
// pred  [16, 2, 256, 256] f32 logits; target [16, 256, 256] i32 {0,1}.
// pred_lbl = (pred[:,1] > pred[:,0]); dt = exact 2D EDT of each mask.
// out = 0.5 * ( mean(pred_lbl * dt(target)) + mean(target * dt(pred_lbl)) )
//
// Row pass: one wave per row, shuffle-based cummax scans (no LDS, no barriers).
// Col pass: radius-bounded exact min-plus. For output pixel (y,x) the
// candidate y'=y gives upper bound U = g2[y,x]; any y' with (y-y')^2 >= U
// cannot win since g2 >= 0. Radius r = floor(sqrt(U))+1 is exact for ANY
// input (empty columns just clamp to the full range). On dense random masks
// r ~ 2, so the inner loop is ~10 iterations instead of 256.

#define B 16
#define H 256
#define W 256
#define IMG (H * W)            // 65536
#define NPIX (B * IMG)         // 1048576
#define NEGF (-1.0e6f)
#define NINF (-3.0e38f)

// ---------------------------------------------------------------------------
// Kernel 1: row pass. One wave (64 lanes) per (m, b, y) row; lane owns x=4l..4l+3.
__global__ __launch_bounds__(256) void rowpass_kernel(
    const float* __restrict__ pred, const int* __restrict__ target,
    float* __restrict__ g2) {
  const int lane = threadIdx.x & 63;
  const int wid = threadIdx.x >> 6;
  const int row = blockIdx.x * 4 + wid;   // [0, 2*B*H)
  const int m = row >> 12;                // 0: pred mask, 1: target mask
  const int bh = row & 4095;
  const int b = bh >> 8;
  const int y = bh & 255;
  const int x0 = lane * 4;

  bool fg[4];
  if (m == 0) {
    const float* base = pred + (size_t)b * (2 * IMG) + y * W + x0;
    const float4 c0 = *(const float4*)(base);
    const float4 c1 = *(const float4*)(base + IMG);
    fg[0] = c1.x > c0.x; fg[1] = c1.y > c0.y;
    fg[2] = c1.z > c0.z; fg[3] = c1.w > c0.w;
  } else {
    const int4 tv = *(const int4*)(target + (size_t)b * IMG + y * W + x0);
    fg[0] = tv.x == 1; fg[1] = tv.y == 1; fg[2] = tv.z == 1; fg[3] = tv.w == 1;
  }

  const float xf0 = (float)x0;

  // ---- left-to-right inclusive cummax of pos_l = fg ? x : NEG
  float p0 = fg[0] ? xf0 : NEGF;
  float p1 = fmaxf(p0, fg[1] ? xf0 + 1.f : NEGF);
  float p2 = fmaxf(p1, fg[2] ? xf0 + 2.f : NEGF);
  float p3 = fmaxf(p2, fg[3] ? xf0 + 3.f : NEGF);
  float s = p3;                            // lane-local max
#pragma unroll
  for (int off = 1; off < 64; off <<= 1) {
    float u = __shfl_up(s, (unsigned)off);
    if (lane >= off) s = fmaxf(s, u);
  }
  float e = __shfl_up(s, 1u);              // exclusive prefix
  if (lane == 0) e = NINF;
  const float dl0 = xf0 - fmaxf(e, p0);
  const float dl1 = xf0 + 1.f - fmaxf(e, p1);
  const float dl2 = xf0 + 2.f - fmaxf(e, p2);
  const float dl3 = xf0 + 3.f - fmaxf(e, p3);

  // ---- right-to-left inclusive cummax of pos_r = fg ? -x : NEG
  float q3 = fg[3] ? -(xf0 + 3.f) : NEGF;
  float q2 = fmaxf(q3, fg[2] ? -(xf0 + 2.f) : NEGF);
  float q1 = fmaxf(q2, fg[1] ? -(xf0 + 1.f) : NEGF);
  float q0 = fmaxf(q1, fg[0] ? -xf0 : NEGF);
  float t = q0;
#pragma unroll
  for (int off = 1; off < 64; off <<= 1) {
    float u = __shfl_down(t, (unsigned)off);
    if (lane < 64 - off) t = fmaxf(t, u);
  }
  float f = __shfl_down(t, 1u);            // exclusive suffix
  if (lane == 63) f = NINF;
  const float dr0 = -fmaxf(f, q0) - xf0;
  const float dr1 = -fmaxf(f, q1) - (xf0 + 1.f);
  const float dr2 = -fmaxf(f, q2) - (xf0 + 2.f);
  const float dr3 = -fmaxf(f, q3) - (xf0 + 3.f);

  float4 o;
  float v;
  v = fminf(dl0, dr0); o.x = v * v;
  v = fminf(dl1, dr1); o.y = v * v;
  v = fminf(dl2, dr2); o.z = v * v;
  v = fminf(dl3, dr3); o.w = v * v;
  *(float4*)(g2 + (size_t)m * NPIX + (size_t)b * IMG + y * W + x0) = o;
}

// ---------------------------------------------------------------------------
// Kernel 2: radius-bounded column min-plus + fused weighted-sum reduction.
// Block = 256 thr handles 64 cols x 16 rows; thread owns 4 consecutive y.
__global__ __launch_bounds__(256) void colpass_kernel(
    const float* __restrict__ g2, const float* __restrict__ pred,
    const int* __restrict__ target, float* __restrict__ sums) {
  const int tid = threadIdx.x;
  const int bi = blockIdx.x;           // [0, 2048)
  const int xt = bi & 3;
  const int yt = (bi >> 2) & 15;
  const int m = (bi >> 6) & 1;
  const int b = bi >> 7;
  const int xin = tid & 63;
  const int ysub = tid >> 6;           // 0..3
  const int x = xt * 64 + xin;
  const int y0 = yt * 16 + ysub * 4;

  const float* __restrict__ gimg = g2 + (size_t)m * NPIX + (size_t)b * IMG;

  float a0 = gimg[(y0 + 0) * W + x];
  float a1 = gimg[(y0 + 1) * W + x];
  float a2 = gimg[(y0 + 2) * W + x];
  float a3 = gimg[(y0 + 3) * W + x];

  const float U = fmaxf(fmaxf(a0, a1), fmaxf(a2, a3));
  const int r = (int)sqrtf(U) + 1;     // exact bound: (y-y')^2 >= U can't win
  int lo = y0 - r; if (lo < 0) lo = 0;
  int hi = y0 + 3 + r; if (hi > H - 1) hi = H - 1;

  for (int yp = lo; yp <= hi; ++yp) {
    const float v = gimg[yp * W + x];
    const float d0 = (float)(y0 - yp);
    const float d1 = d0 + 1.f;
    const float d2 = d0 + 2.f;
    const float d3 = d0 + 3.f;
    a0 = fminf(a0, fmaf(d0, d0, v));
    a1 = fminf(a1, fmaf(d1, d1, v));
    a2 = fminf(a2, fmaf(d2, d2, v));
    a3 = fminf(a3, fmaf(d3, d3, v));
  }

  // epilogue: dt = sqrt(dt2); weight by the OTHER mask; local sum
  float local = 0.f;
  if (m == 0) {
    // dt of pred_lbl, weighted by target
    const int* tg = target + (size_t)b * IMG + y0 * W + x;
    local += (float)tg[0 * W] * sqrtf(a0);
    local += (float)tg[1 * W] * sqrtf(a1);
    local += (float)tg[2 * W] * sqrtf(a2);
    local += (float)tg[3 * W] * sqrtf(a3);
  } else {
    // dt of target, weighted by pred_lbl
    const float* p = pred + (size_t)b * (2 * IMG) + y0 * W + x;
    local += ((p[0 * W + IMG] > p[0 * W]) ? 1.f : 0.f) * sqrtf(a0);
    local += ((p[1 * W + IMG] > p[1 * W]) ? 1.f : 0.f) * sqrtf(a1);
    local += ((p[2 * W + IMG] > p[2 * W]) ? 1.f : 0.f) * sqrtf(a2);
    local += ((p[3 * W + IMG] > p[3 * W]) ? 1.f : 0.f) * sqrtf(a3);
  }

  __shared__ float red[256];
  red[tid] = local;
  __syncthreads();
  for (int s = 128; s > 0; s >>= 1) {
    if (tid < s) red[tid] += red[tid + s];
    __syncthreads();
  }
  if (tid == 0) atomicAdd(&sums[m], red[0]);
}

// ---------------------------------------------------------------------------
__global__ void init_kernel(float* __restrict__ sums) {
  if (threadIdx.x < 2) sums[threadIdx.x] = 0.f;
}

__global__ void finalize_kernel(const float* __restrict__ sums,
                                float* __restrict__ out) {
  out[0] = (sums[0] + sums[1]) * (0.5f / (float)NPIX);
}

// ---------------------------------------------------------------------------
extern "C" void kernel_launch(void* const* d_in, const int* in_sizes, int n_in,
                              void* d_out, int out_size, void* d_ws, size_t ws_size,
                              hipStream_t stream) {
  const float* pred = (const float*)d_in[0];     // [16,2,256,256] f32
  const int* target = (const int*)d_in[1];       // [16,256,256] i32
  float* out = (float*)d_out;                    // scalar f32

  float* g2 = (float*)d_ws;                      // 2 * NPIX floats (8 MB)
  float* sums = g2 + 2 * (size_t)NPIX;           // 2 floats

  init_kernel<<<1, 64, 0, stream>>>(sums);
  rowpass_kernel<<<2 * B * H / 4, 256, 0, stream>>>(pred, target, g2);
  colpass_kernel<<<2048, 256, 0, stream>>>(g2, pred, target, sums);
  finalize_kernel<<<1, 1, 0, stream>>>(sums, out);
}

// Round 3
// 77.700 us; speedup vs baseline: 1.9853x; 1.3079x over previous
//
#include <hip/hip_runtime.h>
#include <hip/hip_bf16.h>
#include <math.h>

// Hausdorff distance loss, exact EDT.
// pred  [16, 2, 256, 256] f32 logits; target [16, 256, 256] i32 {0,1}.
// pred_lbl = (pred[:,1] > pred[:,0]); dt = exact 2D EDT of each mask.
// out = (sum(pred_lbl * dt(target)) + sum(target * dt(pred_lbl))) / (2*NPIX)
//
// Row pass: one wave per row, shuffle-based cummax scans (no LDS/barriers);
// also stashes both binary masks as uchar labels for the col pass epilogue.
// Col pass: radius-bounded exact min-plus (candidate y'=y gives upper bound
// U; any |y-y'| with (y-y')^2 >= U cannot win since g2 >= 0). Per-block
// partial sums -> no atomics. Finalize: one block tree-reduces 2048 partials.

#define B 16
#define H 256
#define W 256
#define IMG (H * W)            // 65536
#define NPIX (B * IMG)         // 1048576
#define NEGF (-1.0e6f)
#define NINF (-3.0e38f)
#define NBLK 2048              // colpass grid

// ---------------------------------------------------------------------------
// Kernel 1: row pass. One wave (64 lanes) per (m, b, y) row; lane owns x=4l..4l+3.
__global__ __launch_bounds__(256) void rowpass_kernel(
    const float* __restrict__ pred, const int* __restrict__ target,
    float* __restrict__ g2, unsigned char* __restrict__ lbl) {
  const int lane = threadIdx.x & 63;
  const int wid = threadIdx.x >> 6;
  const int row = blockIdx.x * 4 + wid;   // [0, 2*B*H)
  const int m = row >> 12;                // 0: pred mask, 1: target mask
  const int bh = row & 4095;
  const int b = bh >> 8;
  const int y = bh & 255;
  const int x0 = lane * 4;

  bool fg[4];
  if (m == 0) {
    const float* base = pred + (size_t)b * (2 * IMG) + y * W + x0;
    const float4 c0 = *(const float4*)(base);
    const float4 c1 = *(const float4*)(base + IMG);
    fg[0] = c1.x > c0.x; fg[1] = c1.y > c0.y;
    fg[2] = c1.z > c0.z; fg[3] = c1.w > c0.w;
  } else {
    const int4 tv = *(const int4*)(target + (size_t)b * IMG + y * W + x0);
    fg[0] = tv.x == 1; fg[1] = tv.y == 1; fg[2] = tv.z == 1; fg[3] = tv.w == 1;
  }

  // stash labels for the colpass epilogue (uchar4 store, coalesced)
  uchar4 lb;
  lb.x = fg[0]; lb.y = fg[1]; lb.z = fg[2]; lb.w = fg[3];
  *(uchar4*)(lbl + (size_t)m * NPIX + (size_t)b * IMG + y * W + x0) = lb;

  const float xf0 = (float)x0;

  // ---- left-to-right inclusive cummax of pos_l = fg ? x : NEG
  float p0 = fg[0] ? xf0 : NEGF;
  float p1 = fmaxf(p0, fg[1] ? xf0 + 1.f : NEGF);
  float p2 = fmaxf(p1, fg[2] ? xf0 + 2.f : NEGF);
  float p3 = fmaxf(p2, fg[3] ? xf0 + 3.f : NEGF);
  float s = p3;                            // lane-local max
#pragma unroll
  for (int off = 1; off < 64; off <<= 1) {
    float u = __shfl_up(s, (unsigned)off);
    if (lane >= off) s = fmaxf(s, u);
  }
  float e = __shfl_up(s, 1u);              // exclusive prefix
  if (lane == 0) e = NINF;
  const float dl0 = xf0 - fmaxf(e, p0);
  const float dl1 = xf0 + 1.f - fmaxf(e, p1);
  const float dl2 = xf0 + 2.f - fmaxf(e, p2);
  const float dl3 = xf0 + 3.f - fmaxf(e, p3);

  // ---- right-to-left inclusive cummax of pos_r = fg ? -x : NEG
  float q3 = fg[3] ? -(xf0 + 3.f) : NEGF;
  float q2 = fmaxf(q3, fg[2] ? -(xf0 + 2.f) : NEGF);
  float q1 = fmaxf(q2, fg[1] ? -(xf0 + 1.f) : NEGF);
  float q0 = fmaxf(q1, fg[0] ? -xf0 : NEGF);
  float t = q0;
#pragma unroll
  for (int off = 1; off < 64; off <<= 1) {
    float u = __shfl_down(t, (unsigned)off);
    if (lane < 64 - off) t = fmaxf(t, u);
  }
  float f = __shfl_down(t, 1u);            // exclusive suffix
  if (lane == 63) f = NINF;
  const float dr0 = -fmaxf(f, q0) - xf0;
  const float dr1 = -fmaxf(f, q1) - (xf0 + 1.f);
  const float dr2 = -fmaxf(f, q2) - (xf0 + 2.f);
  const float dr3 = -fmaxf(f, q3) - (xf0 + 3.f);

  float4 o;
  float v;
  v = fminf(dl0, dr0); o.x = v * v;
  v = fminf(dl1, dr1); o.y = v * v;
  v = fminf(dl2, dr2); o.z = v * v;
  v = fminf(dl3, dr3); o.w = v * v;
  *(float4*)(g2 + (size_t)m * NPIX + (size_t)b * IMG + y * W + x0) = o;
}

// ---------------------------------------------------------------------------
// Kernel 2: radius-bounded column min-plus + fused weighted partial sums.
// Block = 256 thr handles 64 cols x 16 rows; thread owns 4 consecutive y.
// Writes ONE partial per block (no atomics).
__global__ __launch_bounds__(256) void colpass_kernel(
    const float* __restrict__ g2, const unsigned char* __restrict__ lbl,
    float* __restrict__ partials) {
  const int tid = threadIdx.x;
  const int bi = blockIdx.x;           // [0, NBLK)
  const int xt = bi & 3;
  const int yt = (bi >> 2) & 15;
  const int m = (bi >> 6) & 1;
  const int b = bi >> 7;
  const int xin = tid & 63;
  const int ysub = tid >> 6;           // 0..3
  const int x = xt * 64 + xin;
  const int y0 = yt * 16 + ysub * 4;

  const float* __restrict__ gimg = g2 + (size_t)m * NPIX + (size_t)b * IMG;

  float a0 = gimg[(y0 + 0) * W + x];
  float a1 = gimg[(y0 + 1) * W + x];
  float a2 = gimg[(y0 + 2) * W + x];
  float a3 = gimg[(y0 + 3) * W + x];

  const float U = fmaxf(fmaxf(a0, a1), fmaxf(a2, a3));
  const int r = (int)sqrtf(U) + 1;     // exact: (y-y')^2 >= U can't improve
  int lo = y0 - r; if (lo < 0) lo = 0;
  int hi = y0 + 3 + r; if (hi > H - 1) hi = H - 1;

  for (int yp = lo; yp <= hi; ++yp) {
    const float v = gimg[yp * W + x];
    const float d0 = (float)(y0 - yp);
    const float d1 = d0 + 1.f;
    const float d2 = d0 + 2.f;
    const float d3 = d0 + 3.f;
    a0 = fminf(a0, fmaf(d0, d0, v));
    a1 = fminf(a1, fmaf(d1, d1, v));
    a2 = fminf(a2, fmaf(d2, d2, v));
    a3 = fminf(a3, fmaf(d3, d3, v));
  }

  // epilogue: dt = sqrt(dt2), weighted by the OTHER mask's labels
  const unsigned char* wl =
      lbl + (size_t)(1 - m) * NPIX + (size_t)b * IMG + y0 * W + x;
  float local = 0.f;
  local += (float)wl[0 * W] * sqrtf(a0);
  local += (float)wl[1 * W] * sqrtf(a1);
  local += (float)wl[2 * W] * sqrtf(a2);
  local += (float)wl[3 * W] * sqrtf(a3);

  __shared__ float red[256];
  red[tid] = local;
  __syncthreads();
  for (int s = 128; s > 0; s >>= 1) {
    if (tid < s) red[tid] += red[tid + s];
    __syncthreads();
  }
  if (tid == 0) partials[bi] = red[0];
}

// ---------------------------------------------------------------------------
// Kernel 3: reduce NBLK partials -> scalar. One block, deterministic.
__global__ __launch_bounds__(256) void finalize_kernel(
    const float* __restrict__ partials, float* __restrict__ out) {
  const int tid = threadIdx.x;
  float s = 0.f;
#pragma unroll
  for (int i = 0; i < NBLK / 256; ++i) s += partials[i * 256 + tid];
  __shared__ float red[256];
  red[tid] = s;
  __syncthreads();
  for (int k = 128; k > 0; k >>= 1) {
    if (tid < k) red[tid] += red[tid + k];
    __syncthreads();
  }
  if (tid == 0) out[0] = red[0] * (0.5f / (float)NPIX);
}

// ---------------------------------------------------------------------------
extern "C" void kernel_launch(void* const* d_in, const int* in_sizes, int n_in,
                              void* d_out, int out_size, void* d_ws, size_t ws_size,
                              hipStream_t stream) {
  const float* pred = (const float*)d_in[0];     // [16,2,256,256] f32
  const int* target = (const int*)d_in[1];       // [16,256,256] i32
  float* out = (float*)d_out;                    // scalar f32

  float* g2 = (float*)d_ws;                                // 8 MB
  float* partials = g2 + 2 * (size_t)NPIX;                 // NBLK floats
  unsigned char* lbl = (unsigned char*)(partials + NBLK);  // 2 MB

  rowpass_kernel<<<2 * B * H / 4, 256, 0, stream>>>(pred, target, g2, lbl);
  colpass_kernel<<<NBLK, 256, 0, stream>>>(g2, lbl, partials);
  finalize_kernel<<<1, 256, 0, stream>>>(partials, out);
}